// Round 4
// baseline (153.883 us; speedup 1.0000x reference)
//
#include <hip/hip_runtime.h>

// BlockConvolutionLean: out = blockwise-exclusive-cumsum(X @ W^T) + b_eff
// X: [65536, 256] fp32, W: [256, 256] fp32, bias: [8] fp32, out: [65536, 256] fp32
//
// R7: time was invariant (57/58/51 us) while HBM traffic swung 101-201 MB and
// BW 2.0-3.5 TB/s -> NOT bandwidth-bound; per-wave serial latency x thin TLP
// is the wall (occ 34%, nothing saturated). R7 cuts both:
//   - A staged to LDS as BF16 via registers (load f32 -> cvt -> ds_write):
//     pack8 leaves the MFMA critical path (cvt overlaps prior-chunk MFMA),
//     A frag read = ONE ds_read_b128, A ring halves to 2 x 10 KB (rows
//     padded to 80 B -> provably uniform bank spread on frag reads).
//   - 8-way N-split: B = 16 KB/block; LDS total 36 KB + launch_bounds(512,6)
//     -> 3 blocks/CU = 24 waves (75%), vs R6's 16 (50% cap).
//   - Loads issued 3 chunks ahead into 3 statically-indexed reg sets;
//     single counted WAIT_VMCNT per KSTEP sits before cvt+ds_write, NOT
//     before the MFMAs; one sched_barrier per KSTEP (end) only.
//   - XCD-sibling swizzle kept (8 ng-siblings consecutive on one XCD ->
//     panel L2-resident; R6 proved FETCH collapses to ~33 MB).

typedef short short8 __attribute__((ext_vector_type(8)));
typedef short short4v __attribute__((ext_vector_type(4)));
typedef float floatx4 __attribute__((ext_vector_type(4)));
typedef unsigned short ushort4v __attribute__((ext_vector_type(4)));

typedef const __attribute__((address_space(1))) unsigned int* gas_u32p;
typedef __attribute__((address_space(3))) unsigned int* las_u32p;

// s_waitcnt with only vmcnt constrained (gfx9 encoding: vm[3:0]|[15:14],
// exp[6:4]=7, lgkm[11:8]=15)
#define WAIT_VMCNT(n) __builtin_amdgcn_s_waitcnt(0x0F70 | ((n) & 0xF) | ((((n) >> 4) & 0x3) << 14))

__device__ __forceinline__ void gl2lds16(const void* g, void* l) {
    __builtin_amdgcn_global_load_lds((gas_u32p)g, (las_u32p)l, 16, 0, 0);
}

__device__ __forceinline__ unsigned short f2bf(float f) {
    union { float f; unsigned int u; } v;
    v.f = f;
    unsigned int u = v.u + 0x7fffu + ((v.u >> 16) & 1u);  // RNE to bf16
    return (unsigned short)(u >> 16);
}

__device__ __forceinline__ short4v pack4(float4 f) {
    short4v r;
    r[0] = (short)f2bf(f.x); r[1] = (short)f2bf(f.y);
    r[2] = (short)f2bf(f.z); r[3] = (short)f2bf(f.w);
    return r;
}

// ---- Kernel 1: W fp32 -> bf16 into workspace ----
__global__ __launch_bounds__(256) void wconv_kernel(
    const float* __restrict__ W, unsigned short* __restrict__ Wb)
{
    const int i = (blockIdx.x * 256 + threadIdx.x) * 4;
    float4 f = *(const float4*)(W + i);
    ushort4v v;
    v[0] = f2bf(f.x); v[1] = f2bf(f.y); v[2] = f2bf(f.z); v[3] = f2bf(f.w);
    *(ushort4v*)(Wb + i) = v;
}

// ---- Kernel 2: GEMM + blockwise exclusive cumsum epilogue ----
// Block: 512 thr = 8 waves. Block tile M=128 x N=32; wave = 16-row strip.
// acc: 2 nt x f32x4 = 8 regs. A ring: 2 x [128 rows][40 bf16] (pad 80 B).
__global__ __launch_bounds__(512, 6) void bcl_gemm_kernel(
    const float* __restrict__ X, const unsigned short* __restrict__ Wb,
    const float* __restrict__ bias, float* __restrict__ out)
{
    __shared__ __align__(16) unsigned short aB[2][128 * 40];  // 20 KB A ring
    __shared__ __align__(16) unsigned short bW[32 * 256];     // 16 KB B eighth

    const int tid  = threadIdx.x;
    const int lane = tid & 63;
    const int w    = tid >> 6;          // wave 0..7
    const int bx   = blockIdx.x;

    // XCD-sibling swizzle: round-robin puts bx&7 on XCD bx&7. Each XCD owns
    // a contiguous mg range; the 8 ng-siblings of an mg are consecutive
    // blocks on the SAME XCD -> X panel fetched once into that L2.
    const int xcd = bx & 7;
    const int u   = bx >> 3;            // 0..511 within XCD
    const int mg  = xcd * 64 + (u >> 3);
    const int ng  = u & 7;              // N-eighth 0..7

    const int cl = lane & 15;
    const int q  = lane >> 4;

    // A load geometry: per load op, wave covers 8 rows x 128 B full lines.
    // lane -> row (lane>>3), floats (lane&7)*4 .. +4.
    const int srow = lane >> 3;
    const float* gA = X + (size_t)(mg * 128 + w * 16 + srow) * 256 + (lane & 7) * 4;

    // ---- One-time B stage: 16 KB = 512 thr x 2 ops x 16B (from L2).
    // 16B unit s = j*512 + tid holds row n = s>>5, phys seg s&31; global
    // source segment is (s&31) ^ (n&15)  [involution swizzle].
    {
        #pragma unroll
        for (int j = 0; j < 2; ++j) {
            const int n    = j * 16 + w * 2 + (lane >> 5);    // row 0..31
            const int seg  = lane & 31;                       // phys 16B seg
            const int lseg = seg ^ (n & 15);                  // logical seg
            const unsigned short* g =
                Wb + (size_t)(ng * 32 + n) * 256 + lseg * 8;
            gl2lds16(g, &bW[(size_t)(j * 512 + w * 64) * 8]);
        }
    }

    // 3 reg sets, statically indexed ONLY (literal c everywhere — rule #20).
    float4 sA[3][2];

#define LOADA(c, s)                                                            \
    do {                                                                       \
        sA[s][0] = *(const float4*)(gA + (c) * 32);                            \
        sA[s][1] = *(const float4*)(gA + (c) * 32 + 8 * 256);                  \
    } while (0)

    // cvt + write chunk c (rows w*16 + srow, w*16 + srow + 8), bf16, pad 40.
#define WRITEA(c, s)                                                           \
    do {                                                                       \
        *(short4v*)&aB[(c) & 1][(w * 16 + srow) * 40 + (lane & 7) * 4] =       \
            pack4(sA[s][0]);                                                   \
        *(short4v*)&aB[(c) & 1][(w * 16 + srow + 8) * 40 + (lane & 7) * 4] =   \
            pack4(sA[s][1]);                                                   \
    } while (0)

    LOADA(0, 0);
    LOADA(1, 1);
    LOADA(2, 2);
    WAIT_VMCNT(4);        // retire B(2)+load0(2); loads 1,2 stay in flight
    WRITEA(0, 0);
    __syncthreads();      // bW visible to all waves (drains vm — once only)

    floatx4 acc[2];
    acc[0] = (floatx4){0.f, 0.f, 0.f, 0.f};
    acc[1] = (floatx4){0.f, 0.f, 0.f, 0.f};

    // One K step (c literal). MFMAs gated only on lgkm (LDS); the single
    // vmcnt wait retires load(c+1) right before its cvt+ds_write, leaving
    // loads c+2, c+3 in flight (ALLOW = 2 x #{c+2,c+3 <= 7}).
#define KSTEP(c, ALLOW)                                                        \
    do {                                                                       \
        if ((c) + 3 < 8) LOADA((c) + 3, ((c) + 3) % 3);                        \
        short8 a0 = *(const short8*)                                           \
            &aB[(c) & 1][(w * 16 + cl) * 40 + q * 8];                          \
        short8 Bf0 = *(const short8*)                                          \
            &bW[(0 * 16 + cl) * 256 + ((((c) * 4 + q) ^ cl) * 8)];             \
        short8 Bf1 = *(const short8*)                                          \
            &bW[(1 * 16 + cl) * 256 + ((((c) * 4 + q) ^ cl) * 8)];             \
        if ((c) + 1 < 8) {                                                     \
            WAIT_VMCNT(ALLOW);                                                 \
            WRITEA((c) + 1, ((c) + 1) % 3);                                    \
        }                                                                      \
        acc[0] = __builtin_amdgcn_mfma_f32_16x16x32_bf16(a0, Bf0, acc[0],      \
                                                         0, 0, 0);             \
        acc[1] = __builtin_amdgcn_mfma_f32_16x16x32_bf16(a0, Bf1, acc[1],      \
                                                         0, 0, 0);             \
        __builtin_amdgcn_sched_barrier(0);                                     \
    } while (0)

    KSTEP(0, 4);
    KSTEP(1, 4);
    KSTEP(2, 4);
    KSTEP(3, 4);
    KSTEP(4, 4);
    KSTEP(5, 2);
    KSTEP(6, 0);
    KSTEP(7, 0);
#undef KSTEP

    // ---- Epilogue: cumsum + bias, transpose via wave-private LDS, stream out
    // C/D layout: col = cl (n = nt*16+cl), tile-row = q*4 + reg;
    // row%8 = (q&1)*4 + reg, row>>3 = q>>1.
    float be[4];
    {
        const int off = (q & 1) * 4;
        be[0] = bias[off + 0];
        be[1] = bias[off + 1];
        be[2] = bias[off + 2];
        be[3] = bias[off + 3];
        if (off == 0) be[0] += bias[0];   // b_eff[0] = 2*bias[0]
    }

    // Wave-private epi: 8 rows x 32 f32 = 1 KB per half, carved from the
    // wave's OWN 16-row slab (1280 B) of aB[0] (p=0) / aB[1] (p=1).
    float* epi0 = (float*)&aB[0][(w * 16) * 40];
    float* epi1 = (float*)&aB[1][(w * 16) * 40];

    #pragma unroll
    for (int p = 0; p < 2; ++p) {        // 8-row half p of the 16-row tile
        float* epi = p ? epi1 : epi0;
        const bool act = ((q >> 1) == p);
        #pragma unroll
        for (int nt = 0; nt < 2; ++nt) {
            floatx4 v = acc[nt];
            float p1 = v[0];
            float p2 = p1 + v[1];
            float p3 = p2 + v[2];
            float tot = p3 + v[3];
            float below = __shfl_up(tot, 16);   // previous quad's block total
            float p0 = 0.f;
            if (q & 1) { p0 = below; p1 += below; p2 += below; p3 += below; }
            if (act) {
                float* dst = epi + (q & 1) * 4 * 32 + nt * 16 + cl;
                dst[0]  = p0 + be[0];
                dst[32] = p1 + be[1];
                dst[64] = p2 + be[2];
                dst[96] = p3 + be[3];
            }
        }
        // read back 8 rows, store one full 128 B line per out row
        {
            const int r  = lane >> 3;            // 0..7
            const int c8 = lane & 7;
            floatx4 vv = *(const floatx4*)&epi[r * 32 + c8 * 4];
            const size_t grow = (size_t)(mg * 128 + w * 16 + p * 8 + r);
            *(floatx4*)&out[grow * 256 + ng * 32 + c8 * 4] = vv;
        }
    }
#undef LOADA
#undef WRITEA

}

extern "C" void kernel_launch(void* const* d_in, const int* in_sizes, int n_in,
                              void* d_out, int out_size, void* d_ws, size_t ws_size,
                              hipStream_t stream)
{
    const float* X = (const float*)d_in[0];  // seq_vector [8*8192, 256]
    const float* W = (const float*)d_in[1];  // [256, 256]
    const float* B = (const float*)d_in[2];  // [8]
    float* out = (float*)d_out;              // [8*8192, 256]
    unsigned short* Wb = (unsigned short*)d_ws;  // 256*256 bf16 = 128 KB

    wconv_kernel<<<dim3(64), dim3(256), 0, stream>>>(W, Wb);
    bcl_gemm_kernel<<<dim3(4096), dim3(512), 0, stream>>>(X, Wb, B, out);
}

// Round 5
// 128.633 us; speedup vs baseline: 1.1963x; 1.1963x over previous
//
#include <hip/hip_runtime.h>

// BlockConvolutionLean: out = blockwise-exclusive-cumsum(X @ W^T) + b_eff
// X: [65536, 256] fp32, W: [256, 256] fp32, bias: [8] fp32, out: [65536, 256] fp32
//
// R8: R3-R7 fit time = (N-split * 64 MB + 64 MB) / ~6.5 TB/s: the N-split
// siblings stream the same X panel SIMULTANEOUSLY, so all miss L2 together
// and are served by L3 at HBM-class speed -- duplicated A reads were the
// wall, and occupancy fixes (R6/R7: 18->53%) never moved it.
// R8 sets N-split = 1: one block owns all 256 output cols; full bf16 W
// (128 KB) lives in LDS (MI355X 160 KB LDS makes this legal), A ring is
// reg-staged bf16 (2 x 8 KB). Total L2-miss traffic = 64 (X once) + 64
// (out) = 128 MB = roofline minimum.
//   - 512 thr = 8 waves x 16 rows; acc 16 x f32x4 = 64 VGPR; 16 MFMA/KSTEP
//     (A frag reused 16x). 512 blocks, 1 block/CU, 2 rounds.
//   - No manual waitcnt / sched_barrier: all memory ops are compiler-visible
//     C; compiler's counted vmcnt/lgkmcnt are exact (R4/R7 lesson).
//   - All LDS patterns XOR-swizzled; each verified uniform over banks
//     (exactly 8 cy/KB minimum).
//   - Epilogue: one barrier, then bW LDS is recycled as per-wave transpose
//     slabs (16 KB/wave); stores are full 1 KB/row contiguous streams.

typedef short short8 __attribute__((ext_vector_type(8)));
typedef float floatx4 __attribute__((ext_vector_type(4)));
typedef unsigned short ushort4v __attribute__((ext_vector_type(4)));

typedef const __attribute__((address_space(1))) unsigned int* gas_u32p;
typedef __attribute__((address_space(3))) unsigned int* las_u32p;

__device__ __forceinline__ void gl2lds16(const void* g, void* l) {
    __builtin_amdgcn_global_load_lds((gas_u32p)g, (las_u32p)l, 16, 0, 0);
}

__device__ __forceinline__ unsigned short f2bf(float f) {
    union { float f; unsigned int u; } v;
    v.f = f;
    unsigned int u = v.u + 0x7fffu + ((v.u >> 16) & 1u);  // RNE to bf16
    return (unsigned short)(u >> 16);
}

__device__ __forceinline__ short8 pack8(float4 f0, float4 f1) {
    short8 r;
    r[0] = (short)f2bf(f0.x); r[1] = (short)f2bf(f0.y);
    r[2] = (short)f2bf(f0.z); r[3] = (short)f2bf(f0.w);
    r[4] = (short)f2bf(f1.x); r[5] = (short)f2bf(f1.y);
    r[6] = (short)f2bf(f1.z); r[7] = (short)f2bf(f1.w);
    return r;
}

// ---- Kernel 1: W fp32 -> bf16 into workspace ----
__global__ __launch_bounds__(256) void wconv_kernel(
    const float* __restrict__ W, unsigned short* __restrict__ Wb)
{
    const int i = (blockIdx.x * 256 + threadIdx.x) * 4;
    float4 f = *(const float4*)(W + i);
    ushort4v v;
    v[0] = f2bf(f.x); v[1] = f2bf(f.y); v[2] = f2bf(f.z); v[3] = f2bf(f.w);
    *(ushort4v*)(Wb + i) = v;
}

// ---- Kernel 2: GEMM + blockwise exclusive cumsum epilogue ----
// Block: 512 thr = 8 waves. Block tile M=128 x N=256 (FULL N); wave =
// 16-row strip, all 256 cols. acc: 16 nt x f32x4 = 64 VGPR.
__global__ __launch_bounds__(512, 2) void bcl_gemm_kernel(
    const float* __restrict__ X, const unsigned short* __restrict__ Wb,
    const float* __restrict__ bias, float* __restrict__ out)
{
    __shared__ unsigned short bW[256 * 256];    // 128 KB: full W [n][k] bf16
    __shared__ unsigned short aB[2][128 * 32];  // 16 KB A ring [128 r][32 k]

    const int tid  = threadIdx.x;
    const int lane = tid & 63;
    const int w    = tid >> 6;          // wave 0..7
    const int mg   = blockIdx.x;        // 0..511 (no split -> no swizzle need)

    const int cl = lane & 15;
    const int q  = lane >> 4;

    // ---- One-time B stage: 128 KB = 512 thr x 16 ops x 16 B (L2-resident).
    // 16B unit u = j*512 + tid: row n = u>>5, phys seg u&31; global source
    // seg = (u&31) ^ (n&15)  [involution swizzle -> conflict-free reads].
    {
        #pragma unroll
        for (int j = 0; j < 16; ++j) {
            const int u  = j * 512 + tid;
            const int n  = u >> 5;
            const int ls = (u & 31) ^ (n & 15);
            gl2lds16(Wb + (size_t)n * 256 + ls * 8,
                     &bW[(size_t)(j * 512 + w * 64) * 8]);
        }
    }

    // A geometry: thread covers row w*16 + (lane>>2), 8 floats at col
    // (lane&3)*8 within each 32-col chunk. Wave = its OWN 16 rows ->
    // the A ring is wave-private (zero barriers in the main loop).
    const int arow = lane >> 2;          // 0..15
    const int asub = lane & 3;           // 8-float group in chunk
    const float* gA =
        X + (size_t)(mg * 128 + w * 16 + arow) * 256 + asub * 8;

    float4 sA[3][2];                     // 3 chunk-deep reg pipeline (static)

#define LOADA(c, s)                                                           \
    do {                                                                      \
        sA[s][0] = *(const float4*)(gA + (c) * 32);                           \
        sA[s][1] = *(const float4*)(gA + (c) * 32 + 4);                       \
    } while (0)

    // cvt f32->bf16, write 16 B. Row stride 64 B; phys 16B seg =
    // (lane&3) ^ (row&3)  [matches frag-read swizzle: row&3 == cl&3].
#define WRITEA(c, s)                                                          \
    do {                                                                      \
        *(short8*)&aB[(c) & 1][(w * 16 + arow) * 32 +                         \
                               ((asub ^ (arow & 3)) * 8)] =                   \
            pack8(sA[s][0], sA[s][1]);                                        \
    } while (0)

    LOADA(0, 0);
    LOADA(1, 1);
    LOADA(2, 2);
    WRITEA(0, 0);        // compiler inserts exact vmcnt (loads 1,2 in flight)
    __syncthreads();     // bW + chunk0 visible; one-time full drain

    floatx4 acc[16];
    #pragma unroll
    for (int nt = 0; nt < 16; ++nt)
        acc[nt] = (floatx4){0.f, 0.f, 0.f, 0.f};

    // K loop: 8 chunks of 32. Per KSTEP: issue load(c+3), cvt+write(c+1),
    // 1 A-frag ds_read (reused 16x), 16 B-frag ds_reads, 16 MFMAs.
    #pragma unroll
    for (int c = 0; c < 8; ++c) {
        if (c + 3 < 8) LOADA(c + 3, (c + 3) % 3);
        if (c + 1 < 8) WRITEA(c + 1, (c + 1) % 3);

        short8 a0 = *(const short8*)
            &aB[c & 1][(w * 16 + cl) * 32 + ((q ^ (cl & 3)) * 8)];

        #pragma unroll
        for (int g = 0; g < 4; ++g) {
            short8 Bf[4];
            #pragma unroll
            for (int t = 0; t < 4; ++t)
                Bf[t] = *(const short8*)
                    &bW[((g * 4 + t) * 16 + cl) * 256 +
                        (((c * 4 + q) ^ cl) * 8)];
            #pragma unroll
            for (int t = 0; t < 4; ++t)
                acc[g * 4 + t] = __builtin_amdgcn_mfma_f32_16x16x32_bf16(
                    a0, Bf[t], acc[g * 4 + t], 0, 0, 0);
        }
    }
#undef LOADA
#undef WRITEA

    // ---- Epilogue: cumsum + bias, transpose via per-wave LDS slab carved
    // out of bW (all waves done with bW after this barrier), stream out.
    __syncthreads();

    // C/D layout: col = cl (n = nt*16+cl), tile-row = q*4 + reg;
    // row%8 = (q&1)*4 + reg, row>>3 = q>>1.
    float be[4];
    {
        const int off = (q & 1) * 4;
        be[0] = bias[off + 0];
        be[1] = bias[off + 1];
        be[2] = bias[off + 2];
        be[3] = bias[off + 3];
        if (off == 0) be[0] += bias[0];   // b_eff[0] = 2*bias[0]
    }

    // Per-wave slab: 2 halves x 8 rows x 256 f32 = 16 KB (8 waves = 128 KB).
    float* epi0 = (float*)bW + w * 4096;
    float* epi1 = epi0 + 2048;

    #pragma unroll
    for (int p = 0; p < 2; ++p) {        // 8-row half p of the 16-row tile
        float* epi = p ? epi1 : epi0;
        const bool act = ((q >> 1) == p);
        #pragma unroll
        for (int nt = 0; nt < 16; ++nt) {
            floatx4 v = acc[nt];
            float p1 = v[0];
            float p2 = p1 + v[1];
            float p3 = p2 + v[2];
            float tot = p3 + v[3];
            float below = __shfl_up(tot, 16);   // previous quad's block total
            float p0 = 0.f;
            if (q & 1) { p0 = below; p1 += below; p2 += below; p3 += below; }
            if (act) {
                float* dst = epi + (q & 1) * 4 * 256 + nt * 16 + cl;
                dst[0]   = p0 + be[0];
                dst[256] = p1 + be[1];
                dst[512] = p2 + be[2];
                dst[768] = p3 + be[3];
            }
        }
        // read back 8 rows, store full contiguous 1 KB per out row
        #pragma unroll
        for (int k = 0; k < 8; ++k) {
            const int r  = lane >> 3;            // 0..7
            const int c8 = (lane & 7) + k * 8;   // 16B group 0..63
            floatx4 vv = *(const floatx4*)&epi[r * 256 + c8 * 4];
            const size_t grow = (size_t)(mg * 128 + w * 16 + p * 8 + r);
            *(floatx4*)&out[grow * 256 + c8 * 4] = vv;
        }
    }
}

extern "C" void kernel_launch(void* const* d_in, const int* in_sizes, int n_in,
                              void* d_out, int out_size, void* d_ws, size_t ws_size,
                              hipStream_t stream)
{
    const float* X = (const float*)d_in[0];  // seq_vector [8*8192, 256]
    const float* W = (const float*)d_in[1];  // [256, 256]
    const float* B = (const float*)d_in[2];  // [8]
    float* out = (float*)d_out;              // [8*8192, 256]
    unsigned short* Wb = (unsigned short*)d_ws;  // 256*256 bf16 = 128 KB

    wconv_kernel<<<dim3(64), dim3(256), 0, stream>>>(W, Wb);
    bcl_gemm_kernel<<<dim3(512), dim3(512), 0, stream>>>(X, Wb, B, out);
}

// Round 7
// 127.831 us; speedup vs baseline: 1.2038x; 1.0063x over previous
//
#include <hip/hip_runtime.h>

// BlockConvolutionLean: out = blockwise-exclusive-cumsum(X @ W^T) + b_eff
// X: [65536, 256] fp32, W: [256, 256] fp32, bias: [8] fp32, out: [65536, 256] fp32
//
// R9 (re-submit; previous bench died to container infra failure, no verdict):
// R8 (N-split=1, 144 KB LDS) cut dur to 41.4 us with clean traffic
// (34+66 MB) but occ 17%, MfmaUtil 7%, BW 2.5 TB/s: ONE resident block/CU
// runs a serial phase chain (B-stage -> loop -> epilogue -> 128 KB store
// burst) with zero overlap, twice. The bubbles ARE the remaining time.
// R9 keeps R8's zero-barrier wave-private engine bit-for-bit and changes one
// variable: LDS 144->80 KB so TWO blocks co-reside per CU and one block's
// compute fills the other's stage/store bubbles.
//   - bW = half of W (N-split=2): 64 KB; aB ring 16 KB; total 80 KB.
//   - XCD sibling pairing: the 2 ng-siblings of each mg are consecutive
//     blocks on the same XCD -> sibling's duplicate X read is an L2 hit
//     (R6 evidence), HBM-path traffic stays ~64+64 MB.
//   - acc halves to 8 x f32x4; launch_bounds(512,4) caps VGPR at 128
//     (R4 spill trap structurally excluded).
//   - Epilogue slabs carved from bW (8 KB/wave), 512 B contiguous stores.

typedef short short8 __attribute__((ext_vector_type(8)));
typedef float floatx4 __attribute__((ext_vector_type(4)));
typedef unsigned short ushort4v __attribute__((ext_vector_type(4)));

typedef const __attribute__((address_space(1))) unsigned int* gas_u32p;
typedef __attribute__((address_space(3))) unsigned int* las_u32p;

__device__ __forceinline__ void gl2lds16(const void* g, void* l) {
    __builtin_amdgcn_global_load_lds((gas_u32p)g, (las_u32p)l, 16, 0, 0);
}

__device__ __forceinline__ unsigned short f2bf(float f) {
    union { float f; unsigned int u; } v;
    v.f = f;
    unsigned int u = v.u + 0x7fffu + ((v.u >> 16) & 1u);  // RNE to bf16
    return (unsigned short)(u >> 16);
}

__device__ __forceinline__ short8 pack8(float4 f0, float4 f1) {
    short8 r;
    r[0] = (short)f2bf(f0.x); r[1] = (short)f2bf(f0.y);
    r[2] = (short)f2bf(f0.z); r[3] = (short)f2bf(f0.w);
    r[4] = (short)f2bf(f1.x); r[5] = (short)f2bf(f1.y);
    r[6] = (short)f2bf(f1.z); r[7] = (short)f2bf(f1.w);
    return r;
}

// ---- Kernel 1: W fp32 -> bf16 into workspace ----
__global__ __launch_bounds__(256) void wconv_kernel(
    const float* __restrict__ W, unsigned short* __restrict__ Wb)
{
    const int i = (blockIdx.x * 256 + threadIdx.x) * 4;
    float4 f = *(const float4*)(W + i);
    ushort4v v;
    v[0] = f2bf(f.x); v[1] = f2bf(f.y); v[2] = f2bf(f.z); v[3] = f2bf(f.w);
    *(ushort4v*)(Wb + i) = v;
}

// ---- Kernel 2: GEMM + blockwise exclusive cumsum epilogue ----
// Block: 512 thr = 8 waves. Block tile M=128 x N=128; wave = 16-row strip,
// all 128 block cols. acc: 8 nt x f32x4 = 32 VGPR.
__global__ __launch_bounds__(512, 4) void bcl_gemm_kernel(
    const float* __restrict__ X, const unsigned short* __restrict__ Wb,
    const float* __restrict__ bias, float* __restrict__ out)
{
    __shared__ unsigned short bW[128 * 256];    // 64 KB: W half [n][k] bf16
    __shared__ unsigned short aB[2][128 * 32];  // 16 KB A ring [128 r][32 k]

    const int tid  = threadIdx.x;
    const int lane = tid & 63;
    const int w    = tid >> 6;          // wave 0..7
    const int bx   = blockIdx.x;

    // XCD sibling pairing: round-robin puts bx&7 on XCD bx&7; each XCD owns
    // a contiguous mg range and the 2 ng-siblings of an mg are consecutive
    // blocks on that XCD -> sibling X reads are L2 hits.
    const int xcd = bx & 7;
    const int u   = bx >> 3;            // 0..127 within XCD
    const int mg  = xcd * 64 + (u >> 1);
    const int ng  = u & 1;              // N-half 0..1

    const int cl = lane & 15;
    const int q  = lane >> 4;

    // ---- One-time B stage: 64 KB = 512 thr x 8 ops x 16 B (L2-resident).
    // 16B unit u2 = j*512 + tid: row n = u2>>5, phys seg u2&31; global
    // source seg = (u2&31) ^ (n&15)  [involution swizzle].
    {
        #pragma unroll
        for (int j = 0; j < 8; ++j) {
            const int n  = j * 16 + w * 2 + (lane >> 5);      // row 0..127
            const int ls = (lane & 31) ^ (n & 15);
            gl2lds16(Wb + (size_t)(ng * 128 + n) * 256 + ls * 8,
                     &bW[(size_t)(j * 512 + w * 64) * 8]);
        }
    }

    // A geometry (R8 verbatim): thread covers row w*16 + (lane>>2), 8 floats
    // at col (lane&3)*8 within each 32-col chunk. Wave reads ONLY rows it
    // wrote -> A ring is wave-private, zero main-loop barriers.
    const int arow = lane >> 2;          // 0..15
    const int asub = lane & 3;           // 8-float group in chunk
    const float* gA =
        X + (size_t)(mg * 128 + w * 16 + arow) * 256 + asub * 8;

    float4 sA[3][2];                     // 3 chunk-deep reg pipeline (static)

#define LOADA(c, s)                                                           \
    do {                                                                      \
        sA[s][0] = *(const float4*)(gA + (c) * 32);                           \
        sA[s][1] = *(const float4*)(gA + (c) * 32 + 4);                       \
    } while (0)

    // cvt f32->bf16, write 16 B. Phys 16B seg = asub ^ (arow&3)
    // [matches frag-read swizzle: row&3 == cl&3].
#define WRITEA(c, s)                                                          \
    do {                                                                      \
        *(short8*)&aB[(c) & 1][(w * 16 + arow) * 32 +                         \
                               ((asub ^ (arow & 3)) * 8)] =                   \
            pack8(sA[s][0], sA[s][1]);                                        \
    } while (0)

    LOADA(0, 0);
    LOADA(1, 1);
    LOADA(2, 2);
    WRITEA(0, 0);        // compiler inserts exact vmcnt (loads 1,2 in flight)
    __syncthreads();     // bW + chunk0 visible; one-time full drain

    floatx4 acc[8];
    #pragma unroll
    for (int nt = 0; nt < 8; ++nt)
        acc[nt] = (floatx4){0.f, 0.f, 0.f, 0.f};

    // K loop: 8 chunks of 32. Per KSTEP: issue load(c+3), cvt+write(c+1),
    // 1 A-frag ds_read (reused 8x), 8 B-frag ds_reads, 8 MFMAs.
    #pragma unroll
    for (int c = 0; c < 8; ++c) {
        if (c + 3 < 8) LOADA(c + 3, (c + 3) % 3);
        if (c + 1 < 8) WRITEA(c + 1, (c + 1) % 3);

        short8 a0 = *(const short8*)
            &aB[c & 1][(w * 16 + cl) * 32 + ((q ^ (cl & 3)) * 8)];

        #pragma unroll
        for (int g = 0; g < 2; ++g) {
            short8 Bf[4];
            #pragma unroll
            for (int t = 0; t < 4; ++t)
                Bf[t] = *(const short8*)
                    &bW[((g * 4 + t) * 16 + cl) * 256 +
                        (((c * 4 + q) ^ cl) * 8)];
            #pragma unroll
            for (int t = 0; t < 4; ++t)
                acc[g * 4 + t] = __builtin_amdgcn_mfma_f32_16x16x32_bf16(
                    a0, Bf[t], acc[g * 4 + t], 0, 0, 0);
        }
    }
#undef LOADA
#undef WRITEA

    // ---- Epilogue: cumsum + bias, transpose via per-wave LDS slab carved
    // out of bW (all waves done with bW after this barrier), stream out.
    __syncthreads();

    // C/D layout: col = cl (n = nt*16+cl), tile-row = q*4 + reg;
    // row%8 = (q&1)*4 + reg, row>>3 = q>>1.
    float be[4];
    {
        const int off = (q & 1) * 4;
        be[0] = bias[off + 0];
        be[1] = bias[off + 1];
        be[2] = bias[off + 2];
        be[3] = bias[off + 3];
        if (off == 0) be[0] += bias[0];   // b_eff[0] = 2*bias[0]
    }

    // Per-wave slab: 2 halves x 8 rows x 128 f32 = 8 KB (8 waves = 64 KB).
    float* epi0 = (float*)bW + w * 2048;
    float* epi1 = epi0 + 1024;

    #pragma unroll
    for (int p = 0; p < 2; ++p) {        // 8-row half p of the 16-row tile
        float* epi = p ? epi1 : epi0;
        const bool act = ((q >> 1) == p);
        #pragma unroll
        for (int nt = 0; nt < 8; ++nt) {
            floatx4 v = acc[nt];
            float p1 = v[0];
            float p2 = p1 + v[1];
            float p3 = p2 + v[2];
            float tot = p3 + v[3];
            float below = __shfl_up(tot, 16);   // previous quad's block total
            float p0 = 0.f;
            if (q & 1) { p0 = below; p1 += below; p2 += below; p3 += below; }
            if (act) {
                float* dst = epi + (q & 1) * 4 * 128 + nt * 16 + cl;
                dst[0]   = p0 + be[0];
                dst[128] = p1 + be[1];
                dst[256] = p2 + be[2];
                dst[384] = p3 + be[3];
            }
        }
        // read back 8 rows, store contiguous 512 B per out row
        #pragma unroll
        for (int k = 0; k < 4; ++k) {
            const int r  = lane >> 3;            // 0..7
            const int c8 = (lane & 7) + k * 8;   // 16B group 0..31
            floatx4 vv = *(const floatx4*)&epi[r * 128 + c8 * 4];
            const size_t grow = (size_t)(mg * 128 + w * 16 + p * 8 + r);
            *(floatx4*)&out[grow * 256 + ng * 128 + c8 * 4] = vv;
        }
    }
}

extern "C" void kernel_launch(void* const* d_in, const int* in_sizes, int n_in,
                              void* d_out, int out_size, void* d_ws, size_t ws_size,
                              hipStream_t stream)
{
    const float* X = (const float*)d_in[0];  // seq_vector [8*8192, 256]
    const float* W = (const float*)d_in[1];  // [256, 256]
    const float* B = (const float*)d_in[2];  // [8]
    float* out = (float*)d_out;              // [8*8192, 256]
    unsigned short* Wb = (unsigned short*)d_ws;  // 256*256 bf16 = 128 KB

    wconv_kernel<<<dim3(64), dim3(256), 0, stream>>>(W, Wb);
    bcl_gemm_kernel<<<dim3(1024), dim3(512), 0, stream>>>(X, Wb, B, out);
}

// Round 8
// 123.915 us; speedup vs baseline: 1.2418x; 1.0316x over previous
//
#include <hip/hip_runtime.h>

// BlockConvolutionLean: out = blockwise-exclusive-cumsum(X @ W^T) + b_eff
// X: [65536, 256] fp32, W: [256, 256] fp32, bias: [8] fp32, out: [65536, 256] fp32
//
// R10: R3-R9 all sat at 41-58us and 2.4-3.5 TB/s while traffic/occupancy/
// pipelining theories died one by one. The surviving discriminator: the
// harness's own fillBuffer hits 6.4 TB/s with 1KB-contiguous wave
// instructions; every one of our rounds moved 16-128B granules (A-loads
// split 64B sectors across two instructions; stores were 8 rows x 128B).
// Theory: DRAM/fabric efficiency of fine-granule interleaved streams is the
// wall. R10 makes EVERY global access a 1KB-contiguous wave instruction:
//   - A: thread t loads float4 at tile*8K + j*2K + t*16 (wave = 1KB contig,
//     block walks 32KB linearly); cvt to bf16; ds_write into seg-swizzled
//     shared tile.
//   - B: IN REGISTERS (64 VGPR/wave = 32 output cols x 256 K), loaded once
//     from a frag-ORDERED Wb (wconv pre-arranges) as 16 x 1KB contig loads.
//     => N-split=1 (X read once), zero B LDS reads, loop has no vmcnt deps.
//   - Stores: cross-wave transpose via 32KB epi LDS (XOR seg-swizzle);
//     one instruction = one full 1KB output row, perfectly contiguous.
// 512 blocks x 4 tiles(32 rows); 64KB LDS + <=128 VGPR -> 2 blocks/CU.

typedef short short8 __attribute__((ext_vector_type(8)));
typedef short short4v __attribute__((ext_vector_type(4)));
typedef float floatx4 __attribute__((ext_vector_type(4)));
typedef unsigned short ushort4v __attribute__((ext_vector_type(4)));

__device__ __forceinline__ unsigned short f2bf(float f) {
    union { float f; unsigned int u; } v;
    v.f = f;
    unsigned int u = v.u + 0x7fffu + ((v.u >> 16) & 1u);  // RNE to bf16
    return (unsigned short)(u >> 16);
}

__device__ __forceinline__ short4v pack4(float4 f) {
    short4v r;
    r[0] = (short)f2bf(f.x); r[1] = (short)f2bf(f.y);
    r[2] = (short)f2bf(f.z); r[3] = (short)f2bf(f.w);
    return r;
}

// ---- Kernel 1: W fp32 -> FRAG-ORDERED bf16 ----
// Wb layout: [ntile16 0..15][kc 0..7][cl 0..15][q 0..3][8 bf16]  (1KB per
// (ntile,kc) chunk). Lane (q,cl) of a wave then loads its B-fragment for
// (ntile,kc) from a single contiguous 1KB chunk.
__global__ __launch_bounds__(256) void wconv_kernel(
    const float* __restrict__ W, unsigned short* __restrict__ Wb)
{
    const int i = (blockIdx.x * 256 + threadIdx.x) * 4;
    float4 f = *(const float4*)(W + i);
    const int n = i >> 8, k = i & 255;
    const int idx =
        (((n >> 4) * 8 + (k >> 5)) * 64 + (n & 15) * 4 + ((k >> 3) & 3)) * 8 +
        (k & 7);
    ushort4v v;
    v[0] = f2bf(f.x); v[1] = f2bf(f.y); v[2] = f2bf(f.z); v[3] = f2bf(f.w);
    *(ushort4v*)(Wb + idx) = v;
}

// ---- Kernel 2: GEMM + blockwise exclusive cumsum epilogue ----
// Block: 512 thr = 8 waves; wave owns 32 output cols (w*32..+32), B-frags
// persistent in registers. Block processes 4 tiles of 32 rows x 256 cols.
__global__ __launch_bounds__(512, 4) void bcl_gemm_kernel(
    const float* __restrict__ X, const unsigned short* __restrict__ Wb,
    const float* __restrict__ bias, float* __restrict__ out)
{
    __shared__ unsigned short aT[2][32 * 256];  // 2 x 16 KB bf16 A tile
    __shared__ float epi[32 * 256];             // 32 KB transpose slab

    const int tid  = threadIdx.x;
    const int lane = tid & 63;
    const int w    = tid >> 6;          // wave 0..7
    const int cl   = lane & 15;
    const int q    = lane >> 4;

    // ---- B fragments: wave cols w*32..+32; 16 x 1KB contiguous loads.
    // Bf[nt][kc] lane(q,cl) = W[n = (w*2+nt)*16+cl][k = kc*32+q*8 ..+8]
    short8 Bf[2][8];
    #pragma unroll
    for (int nt = 0; nt < 2; ++nt)
        #pragma unroll
        for (int kc = 0; kc < 8; ++kc)
            Bf[nt][kc] = *(const short8*)
                (Wb + ((((w * 2 + nt) * 8 + kc) * 64) + cl * 4 + q) * 8);

    const int tile0 = blockIdx.x * 4;
    float4 sF[4];

    // Wave-contiguous 1KB A loads: thread t covers floats [t*4, t*4+4) of
    // each 2K-float slab j. Row within tile = j*8 + w (uniform per wave op).
#define LOADT(tt)                                                             \
    do {                                                                      \
        const float* _g = X + (size_t)(tt) * 8192 + tid * 4;                  \
        _Pragma("unroll")                                                     \
        for (int _j = 0; _j < 4; ++_j)                                        \
            sF[_j] = *(const float4*)(_g + _j * 2048);                        \
    } while (0)

    // bf16 cvt + ds_write_b64. Logical 16B seg s = lane>>1 of row j*8+w is
    // stored at phys seg s ^ (row&7)  [same involution the frag read uses].
#define WRITET(b)                                                             \
    do {                                                                      \
        _Pragma("unroll")                                                     \
        for (int _j = 0; _j < 4; ++_j) {                                      \
            const int _row = _j * 8 + w;                                      \
            const int _ph  = (lane >> 1) ^ w;  /* row&7 == w */               \
            *(short4v*)&aT[b][_row * 256 + _ph * 8 + (lane & 1) * 4] =        \
                pack4(sF[_j]);                                                \
        }                                                                     \
    } while (0)

    // A-frag read: row mt*16+cl, logical seg kc*4+q at phys seg^(cl&7):
    // bank-uniform (8 lanes per 4-bank group). 16 reads + 32 MFMAs / tile.
#define COMPUTE(b)                                                            \
    do {                                                                      \
        _Pragma("unroll")                                                     \
        for (int kc = 0; kc < 8; ++kc) {                                      \
            _Pragma("unroll")                                                 \
            for (int mt = 0; mt < 2; ++mt) {                                  \
                short8 _a = *(const short8*)                                  \
                    &aT[b][(mt * 16 + cl) * 256 +                             \
                           (((kc * 4 + q) ^ (cl & 7)) << 3)];                 \
                acc[mt][0] = __builtin_amdgcn_mfma_f32_16x16x32_bf16(         \
                    _a, Bf[0][kc], acc[mt][0], 0, 0, 0);                      \
                acc[mt][1] = __builtin_amdgcn_mfma_f32_16x16x32_bf16(         \
                    _a, Bf[1][kc], acc[mt][1], 0, 0, 0);                      \
            }                                                                 \
        }                                                                     \
    } while (0)

    float be[4];
    {
        const int off = (q & 1) * 4;
        be[0] = bias[off + 0];
        be[1] = bias[off + 1];
        be[2] = bias[off + 2];
        be[3] = bias[off + 3];
        if (off == 0) be[0] += bias[0];   // b_eff[0] = 2*bias[0]
    }

    floatx4 acc[2][2];

    LOADT(tile0);
    WRITET(0);
    __syncthreads();

    #pragma unroll
    for (int t = 0; t < 4; ++t) {
        const int tile = tile0 + t;
        if (t + 1 < 4) LOADT(tile + 1);    // issue next-tile loads early

        #pragma unroll
        for (int mt = 0; mt < 2; ++mt)
            #pragma unroll
            for (int nt = 0; nt < 2; ++nt)
                acc[mt][nt] = (floatx4){0.f, 0.f, 0.f, 0.f};

        COMPUTE(t & 1);
        if (t + 1 < 4) WRITET((t + 1) & 1);  // vmcnt wait lands here (covered)

        // ---- cumsum + bias -> epi (seg-swizzled: phys = seg ^ (q<<2);
        // (row>>2)&3 == q for rows mt*16+q*4+reg).
        #pragma unroll
        for (int mt = 0; mt < 2; ++mt)
            #pragma unroll
            for (int nt = 0; nt < 2; ++nt) {
                floatx4 v = acc[mt][nt];
                float p1 = v[0];
                float p2 = p1 + v[1];
                float p3 = p2 + v[2];
                float tot = p3 + v[3];
                float below = __shfl_up(tot, 16);  // previous quad's total
                float p0 = 0.f;
                if (q & 1) { p0 = below; p1 += below; p2 += below; p3 += below; }
                const int rbase = mt * 16 + q * 4;
                const int ph = (w * 8 + nt * 4 + (cl >> 2)) ^ (q << 2);
                float* dst = &epi[rbase * 256 + ph * 4 + (cl & 3)];
                dst[0]   = p0 + be[0];
                dst[256] = p1 + be[1];
                dst[512] = p2 + be[2];
                dst[768] = p3 + be[3];
            }
        __syncthreads();

        // ---- read back 4 full rows per wave; unswizzle: logical seg ==
        // lane; store = one 1KB-contiguous instruction per row.
        #pragma unroll
        for (int k = 0; k < 4; ++k) {
            const int row = w * 4 + k;     // row>>2 == w
            floatx4 vv = *(const floatx4*)
                &epi[row * 256 + ((lane ^ ((w & 3) << 2)) << 2)];
            *(floatx4*)&out[(size_t)(tile * 32 + row) * 256 + lane * 4] = vv;
        }
        if (t + 1 < 4) __syncthreads();    // epi reusable next tile
    }
#undef LOADT
#undef WRITET
#undef COMPUTE
}

extern "C" void kernel_launch(void* const* d_in, const int* in_sizes, int n_in,
                              void* d_out, int out_size, void* d_ws, size_t ws_size,
                              hipStream_t stream)
{
    const float* X = (const float*)d_in[0];  // seq_vector [8*8192, 256]
    const float* W = (const float*)d_in[1];  // [256, 256]
    const float* B = (const float*)d_in[2];  // [8]
    float* out = (float*)d_out;              // [8*8192, 256]
    unsigned short* Wb = (unsigned short*)d_ws;  // 128 KB frag-ordered bf16

    wconv_kernel<<<dim3(64), dim3(256), 0, stream>>>(W, Wb);
    bcl_gemm_kernel<<<dim3(512), dim3(512), 0, stream>>>(X, Wb, B, out);
}

// Round 9
// 123.248 us; speedup vs baseline: 1.2486x; 1.0054x over previous
//
#include <hip/hip_runtime.h>

// BlockConvolutionLean: out = blockwise-exclusive-cumsum(X @ W^T) + b_eff
// X: [65536, 256] fp32, W: [256, 256] fp32, bias: [8] fp32, out: [65536, 256] fp32
//
// R11: R10 (all-1KB-contiguous access) improved to ~37us but BW still capped
// ~2.7 TB/s. Little's law: 6.3 TB/s @ ~900cy latency needs ~9.2 KB/CU
// outstanding CONTINUOUSLY; R10's 2-3 __syncthreads per tile each compile to
// s_waitcnt vmcnt(0) lgkmcnt(0) + s_barrier -- full queue drains, ~3x/tile,
// so average outstanding (and thus device BW) sat at ~40%. This mechanism
// explains every round's 2.4-3.5 TB/s cap.
// R11 keeps R10's data plan (1KB wave-contiguous loads/stores, B-in-regs,
// X read once) and changes ONLY the sync discipline (T3/T4):
//   - raw s_barrier + lgkmcnt(0)-only waits in the loop; vmcnt NEVER drained.
//   - depth-2 tile prefetch (sF[2][4], aT ring-3): the compiler's exactly-
//     counted vmcnt wait for sF retires loads issued a full tile earlier.
//   - stores issued after loads each tile -> counted waits never drain them.
//   - launch_bounds(512,3): VGPR ~137 fits w/o spill; 80KB LDS; 8 waves/CU.

typedef short short8 __attribute__((ext_vector_type(8)));
typedef short short4v __attribute__((ext_vector_type(4)));
typedef float floatx4 __attribute__((ext_vector_type(4)));
typedef unsigned short ushort4v __attribute__((ext_vector_type(4)));

// lgkmcnt(0) ONLY (vmcnt=63 unconstrained, expcnt=7):
// bits [3:0]=vm lo, [6:4]=exp, [11:8]=lgkm, [15:14]=vm hi -> 0xC07F
#define LGKM0_BAR()                                                           \
    do {                                                                      \
        __builtin_amdgcn_s_waitcnt(0xC07F);                                   \
        __builtin_amdgcn_s_barrier();                                         \
    } while (0)

__device__ __forceinline__ unsigned short f2bf(float f) {
    union { float f; unsigned int u; } v;
    v.f = f;
    unsigned int u = v.u + 0x7fffu + ((v.u >> 16) & 1u);  // RNE to bf16
    return (unsigned short)(u >> 16);
}

__device__ __forceinline__ short4v pack4(float4 f) {
    short4v r;
    r[0] = (short)f2bf(f.x); r[1] = (short)f2bf(f.y);
    r[2] = (short)f2bf(f.z); r[3] = (short)f2bf(f.w);
    return r;
}

// ---- Kernel 1: W fp32 -> FRAG-ORDERED bf16 ----
// Wb layout: [ntile16][kc][cl][q][8 bf16] (1KB per (ntile,kc) chunk) so a
// wave's B-frag load for (ntile,kc) is one contiguous 1KB wave access.
__global__ __launch_bounds__(256) void wconv_kernel(
    const float* __restrict__ W, unsigned short* __restrict__ Wb)
{
    const int i = (blockIdx.x * 256 + threadIdx.x) * 4;
    float4 f = *(const float4*)(W + i);
    const int n = i >> 8, k = i & 255;
    const int idx =
        (((n >> 4) * 8 + (k >> 5)) * 64 + (n & 15) * 4 + ((k >> 3) & 3)) * 8 +
        (k & 7);
    ushort4v v;
    v[0] = f2bf(f.x); v[1] = f2bf(f.y); v[2] = f2bf(f.z); v[3] = f2bf(f.w);
    *(ushort4v*)(Wb + idx) = v;
}

// ---- Kernel 2: GEMM + blockwise exclusive cumsum epilogue ----
// Block: 512 thr = 8 waves; wave owns 32 output cols, B persistent in regs.
// Block processes 4 tiles of 32 rows x 256 cols. No vmcnt drains anywhere.
__global__ __launch_bounds__(512, 3) void bcl_gemm_kernel(
    const float* __restrict__ X, const unsigned short* __restrict__ Wb,
    const float* __restrict__ bias, float* __restrict__ out)
{
    __shared__ unsigned short aT[3][32 * 256];  // 3 x 16 KB bf16 A ring
    __shared__ float epi[32 * 256];             // 32 KB transpose slab

    const int tid  = threadIdx.x;
    const int lane = tid & 63;
    const int w    = tid >> 6;          // wave 0..7
    const int cl   = lane & 15;
    const int q    = lane >> 4;

    // ---- B fragments: wave cols w*32..+32; 16 x 1KB contiguous loads.
    short8 Bf[2][8];
    #pragma unroll
    for (int nt = 0; nt < 2; ++nt)
        #pragma unroll
        for (int kc = 0; kc < 8; ++kc)
            Bf[nt][kc] = *(const short8*)
                (Wb + ((((w * 2 + nt) * 8 + kc) * 64) + cl * 4 + q) * 8);

    const int tile0 = blockIdx.x * 4;
    float4 sF[2][4];                    // depth-2 tile prefetch (static idx)

    // 1KB wave-contiguous A loads: thread t covers floats [t*4,t*4+4) of
    // each 2K-float slab; 4 slabs = one 32-row tile (block walks 32KB).
#define LOADT(tt)                                                             \
    do {                                                                      \
        const float* _g = X + (size_t)(tile0 + (tt)) * 8192 + tid * 4;        \
        _Pragma("unroll")                                                     \
        for (int _j = 0; _j < 4; ++_j)                                        \
            sF[(tt) & 1][_j] = *(const float4*)(_g + _j * 2048);              \
    } while (0)

    // cvt + ds_write_b64; logical 16B seg (lane>>1) of row _j*8+w stored at
    // phys seg ^ w (row&7 == w) -- involution matched by the frag read.
#define WRITET(tt)                                                            \
    do {                                                                      \
        _Pragma("unroll")                                                     \
        for (int _j = 0; _j < 4; ++_j) {                                      \
            const int _row = _j * 8 + w;                                      \
            const int _ph  = (lane >> 1) ^ w;                                 \
            *(short4v*)&aT[(tt) % 3][_row * 256 + _ph * 8 + (lane & 1) * 4]   \
                = pack4(sF[(tt) & 1][_j]);                                    \
        }                                                                     \
    } while (0)

    // A-frag: row mt*16+cl, logical seg kc*4+q at phys seg^(cl&7).
#define COMPUTE(tt)                                                           \
    do {                                                                      \
        _Pragma("unroll")                                                     \
        for (int mt = 0; mt < 2; ++mt)                                        \
            _Pragma("unroll")                                                 \
            for (int nt = 0; nt < 2; ++nt)                                    \
                acc[mt][nt] = (floatx4){0.f, 0.f, 0.f, 0.f};                  \
        _Pragma("unroll")                                                     \
        for (int kc = 0; kc < 8; ++kc)                                        \
            _Pragma("unroll")                                                 \
            for (int mt = 0; mt < 2; ++mt) {                                  \
                short8 _a = *(const short8*)                                  \
                    &aT[(tt) % 3][(mt * 16 + cl) * 256 +                      \
                                  (((kc * 4 + q) ^ (cl & 7)) << 3)];          \
                acc[mt][0] = __builtin_amdgcn_mfma_f32_16x16x32_bf16(         \
                    _a, Bf[0][kc], acc[mt][0], 0, 0, 0);                      \
                acc[mt][1] = __builtin_amdgcn_mfma_f32_16x16x32_bf16(         \
                    _a, Bf[1][kc], acc[mt][1], 0, 0, 0);                      \
            }                                                                 \
    } while (0)

    // cumsum + bias -> epi (seg-swizzled: phys = seg ^ (q<<2)).
#define EPI(tt)                                                               \
    do {                                                                      \
        _Pragma("unroll")                                                     \
        for (int mt = 0; mt < 2; ++mt)                                        \
            _Pragma("unroll")                                                 \
            for (int nt = 0; nt < 2; ++nt) {                                  \
                floatx4 v = acc[mt][nt];                                      \
                float p1 = v[0];                                              \
                float p2 = p1 + v[1];                                         \
                float p3 = p2 + v[2];                                         \
                float tot = p3 + v[3];                                        \
                float below = __shfl_up(tot, 16);                             \
                float p0 = 0.f;                                               \
                if (q & 1) { p0 = below; p1 += below; p2 += below;            \
                             p3 += below; }                                   \
                const int rbase = mt * 16 + q * 4;                            \
                const int ph = (w * 8 + nt * 4 + (cl >> 2)) ^ (q << 2);       \
                float* dst = &epi[rbase * 256 + ph * 4 + (cl & 3)];           \
                dst[0]   = p0 + be[0];                                        \
                dst[256] = p1 + be[1];                                        \
                dst[512] = p2 + be[2];                                        \
                dst[768] = p3 + be[3];                                        \
            }                                                                 \
    } while (0)

    // readback 4 rows/wave (unswizzle: logical seg == lane), 1KB stores.
#define RBSTORE(tt)                                                           \
    do {                                                                      \
        _Pragma("unroll")                                                     \
        for (int _k = 0; _k < 4; ++_k) {                                      \
            const int _row = w * 4 + _k;                                      \
            floatx4 vv = *(const floatx4*)                                    \
                &epi[_row * 256 + ((lane ^ ((w & 3) << 2)) << 2)];            \
            *(floatx4*)&out[(size_t)((tile0 + (tt)) * 32 + _row) * 256 +      \
                            lane * 4] = vv;                                   \
        }                                                                     \
    } while (0)

    float be[4];
    {
        const int off = (q & 1) * 4;
        be[0] = bias[off + 0];
        be[1] = bias[off + 1];
        be[2] = bias[off + 2];
        be[3] = bias[off + 3];
        if (off == 0) be[0] += bias[0];   // b_eff[0] = 2*bias[0]
    }

    floatx4 acc[2][2];

    // ---- Prologue: B(16), L0(4), L1(4) issued; compiler's counted wait for
    // sF[0] (vmcnt 4) retires B+L0 and leaves L1 flying.
    LOADT(0);
    LOADT(1);
    WRITET(0);
    LGKM0_BAR();          // publish aT[0]; L1 stays in flight

    // ---- Tile 0
    LOADT(2);             // queue: [L1, L2]
    COMPUTE(0);
    WRITET(1);            // auto vmcnt(4): retires L1, L2 flying
    LGKM0_BAR();          // publish aT[1]
    EPI(0);
    LGKM0_BAR();          // epi visible
    RBSTORE(0);           // stores S0 fire-and-forget

    // ---- Tile 1
    LOADT(3);             // queue: [L2, S0, L3]
    COMPUTE(1);
    WRITET(2);            // auto vmcnt(8): retires L2; S0+L3 flying
    LGKM0_BAR();
    EPI(1);
    LGKM0_BAR();
    RBSTORE(1);           // S1

    // ---- Tile 2
    COMPUTE(2);           // queue: [L3, S1]
    WRITET(3);            // auto vmcnt(4): retires L3; S1 flying
    LGKM0_BAR();
    EPI(2);
    LGKM0_BAR();
    RBSTORE(2);           // S2

    // ---- Tile 3
    COMPUTE(3);
    LGKM0_BAR();          // order: prior RB reads done before epi overwrite
    EPI(3);
    LGKM0_BAR();
    RBSTORE(3);           // S3 drains at kernel end
#undef LOADT
#undef WRITET
#undef COMPUTE
#undef EPI
#undef RBSTORE
}

extern "C" void kernel_launch(void* const* d_in, const int* in_sizes, int n_in,
                              void* d_out, int out_size, void* d_ws, size_t ws_size,
                              hipStream_t stream)
{
    const float* X = (const float*)d_in[0];  // seq_vector [8*8192, 256]
    const float* W = (const float*)d_in[1];  // [256, 256]
    const float* B = (const float*)d_in[2];  // [8]
    float* out = (float*)d_out;              // [8*8192, 256]
    unsigned short* Wb = (unsigned short*)d_ws;  // 128 KB frag-ordered bf16

    wconv_kernel<<<dim3(64), dim3(256), 0, stream>>>(W, Wb);
    bcl_gemm_kernel<<<dim3(512), dim3(512), 0, stream>>>(X, Wb, B, out);
}